// Round 8
// baseline (244.670 us; speedup 1.0000x reference)
//
#include <hip/hip_runtime.h>

typedef __bf16 bf16_t;
typedef __attribute__((ext_vector_type(8))) __bf16 bf16x8;
typedef __attribute__((ext_vector_type(4))) __bf16 bf16x4;
typedef __attribute__((ext_vector_type(4))) float f32x4;
typedef __attribute__((ext_vector_type(16))) float f32x16;

#define B_  4
#define L_  2048
#define D_  1024
#define M_  (B_*L_)
#define N3_ (3*D_)

__device__ __forceinline__ void gload_lds16(const void* g, void* l) {
  __builtin_amdgcn_global_load_lds(
      (__attribute__((address_space(1))) void*)(g),
      (__attribute__((address_space(3))) void*)(l), 16, 0, 0);
}

// Stage one 128-row x 64-col bf16 half-tile into LDS. LDS dest linear; global
// source column pre-swizzled (chunk ^= row&7) so swizzled ds_reads are
// bank-conflict-free (T2, m173 pattern). 512 threads, 2 gload issues.
__device__ __forceinline__ void stage_half(const bf16_t* __restrict__ g, int ld, int grow0,
                                           int k0, bf16_t* lds_tile, int h, int tid) {
  const int lane = tid & 63;
  const int csrc = ((lane & 7) ^ (lane >> 3)) << 3;
  const int rsub = tid >> 3;
  bf16_t* l0 = lds_tile + (size_t)(h * 128 + ((tid >> 6) << 3)) * 64;
  const bf16_t* g0 = g + (size_t)(grow0 + h * 128 + rsub) * ld + (k0 + csrc);
  gload_lds16(g0, l0);
  gload_lds16(g0 + (size_t)64 * ld, l0 + 64 * 64);
}

// read 12 frags (A: 4 M-frags x 2 ks, B: 2 N-frags x 2 ks) for one phase
#define READ12(dA, dB, bufA, bufB, cku, ckv)                                      \
  do {                                                                            \
    _Pragma("unroll")                                                             \
    for (int mi = 0; mi < 4; ++mi) {                                              \
      dA[mi][0] = *(const bf16x8*)((bufA) + aoff + mi * 2048 + (cku));            \
      dA[mi][1] = *(const bf16x8*)((bufA) + aoff + mi * 2048 + (ckv));            \
    }                                                                             \
    _Pragma("unroll")                                                             \
    for (int ni = 0; ni < 2; ++ni) {                                              \
      dB[ni][0] = *(const bf16x8*)((bufB) + boff + ni * 2048 + (cku));            \
      dB[ni][1] = *(const bf16x8*)((bufB) + boff + ni * 2048 + (ckv));            \
    }                                                                             \
  } while (0)

// 16 x mfma_f32_32x32x16_bf16, operand-swapped (B as first operand) so the
// C/D frag holds M-row = lane&31 and 4-consecutive N-cols per reg-quad.
#define MFMA16(fA, fB)                                                            \
  do {                                                                            \
    __builtin_amdgcn_s_setprio(1);                                                \
    _Pragma("unroll")                                                             \
    for (int mi = 0; mi < 4; ++mi)                                                \
      _Pragma("unroll")                                                           \
      for (int ni = 0; ni < 2; ++ni) {                                            \
        acc[mi][ni] = __builtin_amdgcn_mfma_f32_32x32x16_bf16(                    \
            fB[ni][0], fA[mi][0], acc[mi][ni], 0, 0, 0);                          \
        acc[mi][ni] = __builtin_amdgcn_mfma_f32_32x32x16_bf16(                    \
            fB[ni][1], fA[mi][1], acc[mi][ni], 0, 0, 0);                          \
      }                                                                           \
    __builtin_amdgcn_s_setprio(0);                                                \
  } while (0)

// P0(j): read ks23(j) -> FB; lgkm(12) gates FA (read in P1(j-1)); MFMA ks01(j);
//        vmcnt(0) completes tile j+1 staging (issued P1(j-1)); barrier.
#define PHASE0(j_)                                                                \
  do {                                                                            \
    bf16_t* Ab = sAl + ((j_) & 1) * 16384;                                        \
    bf16_t* Bb = sBl + ((j_) & 1) * 16384;                                        \
    READ12(fbA, fbB, Ab, Bb, ck2, ck3);                                           \
    asm volatile("s_waitcnt lgkmcnt(12)" ::: "memory");                           \
    __builtin_amdgcn_sched_barrier(0);                                            \
    MFMA16(faA, faB);                                                             \
    asm volatile("s_waitcnt vmcnt(0)" ::: "memory");                              \
    asm volatile("s_barrier" ::: "memory");                                       \
  } while (0)

// P1(j): read ks01(j+1) -> FA; stage tile j+2 into tile-j's bufs (8 gloads,
//        left in flight across the barrier); lgkm(12) gates FB; MFMA ks23(j).
#define PHASE1(j_)                                                                \
  do {                                                                            \
    if ((j_) + 1 < NT) {                                                          \
      bf16_t* An = sAl + (((j_) + 1) & 1) * 16384;                                \
      bf16_t* Bn = sBl + (((j_) + 1) & 1) * 16384;                                \
      READ12(faA, faB, An, Bn, ck0, ck1);                                         \
      if ((j_) + 2 < NT) {                                                        \
        bf16_t* As = sAl + ((j_) & 1) * 16384;                                    \
        bf16_t* Bs = sBl + ((j_) & 1) * 16384;                                    \
        stage_half(A,  lda, r0, ((j_) + 2) * 64, As, 0, tid);                     \
        stage_half(A,  lda, r0, ((j_) + 2) * 64, As, 1, tid);                     \
        stage_half(Bt, ldb, c0, ((j_) + 2) * 64, Bs, 0, tid);                     \
        stage_half(Bt, ldb, c0, ((j_) + 2) * 64, Bs, 1, tid);                     \
      }                                                                           \
      asm volatile("s_waitcnt lgkmcnt(12)" ::: "memory");                         \
    } else {                                                                      \
      asm volatile("s_waitcnt lgkmcnt(0)" ::: "memory");                          \
    }                                                                             \
    __builtin_amdgcn_sched_barrier(0);                                            \
    MFMA16(fbA, fbB);                                                             \
    asm volatile("s_barrier" ::: "memory");                                       \
  } while (0)

// C[M][N] = A[M][K] * Bt[N][K]^T (+bias). 256x256 tile, BK=64, 512 threads
// (8 waves 2M x 4N, wave out 128x64 as 4x2 frags of 32x32x16). 2-phase K-tile
// with fragment read-ahead; A/B double-buffered (128 KiB). XCD swizzle (T1).
template<bool OUT_BF16, bool CAUSAL, bool VARK, bool PROJ>
__global__ __launch_bounds__(512, 2)
void gemm32(const bf16_t* __restrict__ A, int lda, long sA,
            const bf16_t* __restrict__ Bt, int ldb, long sB,
            void* __restrict__ Cv, int ldc, long sC,
            const float* __restrict__ b0, const float* __restrict__ b1,
            const float* __restrict__ b2, int K)
{
  const int gx = gridDim.x;
  const int nwg = gx * gridDim.y;
  const int orig = blockIdx.y * gx + blockIdx.x;
  const int swzb = (orig & 7) * (nwg >> 3) + (orig >> 3);   // bijective: nwg % 8 == 0
  const int bx = swzb % gx, by = swzb / gx;
  if (CAUSAL && bx > by) return;

  const int z = blockIdx.z;
  A  += (size_t)z * sA;
  Bt += (size_t)z * sB;

  const int r0 = by * 256, c0 = bx * 256;
  const int kend = VARK ? min(K, r0 + 256) : K;
  const int NT = kend >> 6;   // >= 4

  extern __shared__ __align__(16) bf16_t smem[];
  bf16_t* sAl = smem;              // 2 x [256*64] A dbuf (64 KiB)
  bf16_t* sBl = smem + 32768;      // 2 x [256*64] B dbuf (64 KiB)

  const int tid = threadIdx.x;
  const int wid = tid >> 6, lane = tid & 63;
  const int wm = wid >> 2, wn = wid & 3;       // 2M x 4N waves
  const int rl = lane & 31, hi = lane >> 5, swz = lane & 7;
  // swizzled 16B-chunk offsets (elements) for k-steps 0..3
  const int ck0 = ((0 + hi) ^ swz) << 3;
  const int ck1 = ((2 + hi) ^ swz) << 3;
  const int ck2 = ((4 + hi) ^ swz) << 3;
  const int ck3 = ((6 + hi) ^ swz) << 3;
  const int aoff = (wm * 128 + rl) * 64;       // + mi*2048 + ck
  const int boff = (wn * 64 + rl) * 64;        // + ni*2048 + ck

  f32x16 acc[4][2] = {};
  bf16x8 faA[4][2], faB[2][2];   // ks01 fragment set
  bf16x8 fbA[4][2], fbB[2][2];   // ks23 fragment set

  // prologue: stage tiles 0 and 1; complete tile 0, leave tile 1 in flight;
  // read tile-0 ks01 frags (the batch P0(0)'s lgkm(12) will gate).
  stage_half(A,  lda, r0, 0,  sAl, 0, tid);
  stage_half(A,  lda, r0, 0,  sAl, 1, tid);
  stage_half(Bt, ldb, c0, 0,  sBl, 0, tid);
  stage_half(Bt, ldb, c0, 0,  sBl, 1, tid);
  stage_half(A,  lda, r0, 64, sAl + 16384, 0, tid);
  stage_half(A,  lda, r0, 64, sAl + 16384, 1, tid);
  stage_half(Bt, ldb, c0, 64, sBl + 16384, 0, tid);
  stage_half(Bt, ldb, c0, 64, sBl + 16384, 1, tid);
  asm volatile("s_waitcnt vmcnt(8)" ::: "memory");
  asm volatile("s_barrier" ::: "memory");
  READ12(faA, faB, sAl, sBl, ck0, ck1);

  for (int j = 0; j < NT; ++j) {
    PHASE0(j);
    PHASE1(j);
  }

  // epilogue: M-row = r0+wm*128+mi*32+(lane&31); per reg-quad g the 4 values
  // are N-cols c..c+3 at c = c0+wn*64+ni*32+g*8+(lane>>5)*4.
  const int cb4 = hi * 4;
  #pragma unroll
  for (int mi = 0; mi < 4; ++mi) {
    const int r = r0 + wm * 128 + mi * 32 + rl;
    #pragma unroll
    for (int ni = 0; ni < 2; ++ni) {
      #pragma unroll
      for (int g = 0; g < 4; ++g) {
        const int c = c0 + wn * 64 + ni * 32 + g * 8 + cb4;
        f32x4 v = { acc[mi][ni][g*4+0], acc[mi][ni][g*4+1],
                    acc[mi][ni][g*4+2], acc[mi][ni][g*4+3] };
        if (PROJ) {
          const float* bias = (c < D_) ? b0 : (c < 2 * D_) ? b1 : b2;
          const float4 bb = *(const float4*)(bias + (c & (D_ - 1)));
          const float sc = (c < D_) ? 0.03125f : 1.0f;   // q pre-scaled by 1/sqrt(D)
          v[0] = (v[0] + bb.x) * sc; v[1] = (v[1] + bb.y) * sc;
          v[2] = (v[2] + bb.z) * sc; v[3] = (v[3] + bb.w) * sc;
        }
        if (OUT_BF16) {
          bf16x4 o = {(bf16_t)v[0], (bf16_t)v[1], (bf16_t)v[2], (bf16_t)v[3]};
          *(bf16x4*)((bf16_t*)Cv + (size_t)z * sC + (size_t)r * ldc + c) = o;
        } else {
          *(f32x4*)((float*)Cv + (size_t)z * sC + (size_t)r * ldc + c) = v;
        }
      }
    }
  }
}

__device__ __forceinline__ float blk_red_max(float v, float* red, int lane, int wid) {
  #pragma unroll
  for (int o = 32; o; o >>= 1) v = fmaxf(v, __shfl_down(v, o));
  __syncthreads();
  if (lane == 0) red[wid] = v;
  __syncthreads();
  return fmaxf(fmaxf(red[0], red[1]), fmaxf(red[2], red[3]));
}
__device__ __forceinline__ float blk_red_sum(float v, float* red, int lane, int wid) {
  #pragma unroll
  for (int o = 32; o; o >>= 1) v += __shfl_down(v, o);
  __syncthreads();
  if (lane == 0) red[wid] = v;
  __syncthreads();
  return red[0] + red[1] + red[2] + red[3];
}

// block (x=row r, y=batch); softmax over bf16 S[r][0..r], write bf16 P,
// zero-fill to 256-aligned end (PV K-tiles span to r0+256).
__global__ __launch_bounds__(256)
void softmax_causal(const bf16_t* __restrict__ S, bf16_t* __restrict__ P) {
  const int r = blockIdx.x;
  const int n = r + 1;
  const int kend = min(((n + 255) >> 8) << 8, L_);
  const bf16_t* row = S + (size_t)blockIdx.y * L_ * L_ + (size_t)r * L_;
  bf16_t* prow = P + (size_t)blockIdx.y * L_ * L_ + (size_t)r * L_;
  const int tid = threadIdx.x, lane = tid & 63, wid = tid >> 6;
  __shared__ float red[4];

  float s[8];
  #pragma unroll
  for (int i = 0; i < 8; ++i) {
    const int c = tid + i * 256;
    s[i] = (c < n) ? (float)row[c] : -3.402823466e38f;
  }
  float mx = -3.402823466e38f;
  #pragma unroll
  for (int i = 0; i < 8; ++i) mx = fmaxf(mx, s[i]);
  mx = blk_red_max(mx, red, lane, wid);

  float e[8]; float sum = 0.f;
  #pragma unroll
  for (int i = 0; i < 8; ++i) {
    const int c = tid + i * 256;
    const float v = (c < n) ? __expf(s[i] - mx) : 0.f;
    e[i] = v; sum += v;
  }
  sum = blk_red_sum(sum, red, lane, wid);
  const float inv = 1.0f / sum;
  #pragma unroll
  for (int i = 0; i < 8; ++i) {
    const int c = tid + i * 256;
    if (c < kend) prow[c] = (bf16_t)(e[i] * inv);   // e==0 in [n,kend) -> zeros
  }
}

__global__ void cvt_f32_bf16(const float* __restrict__ in, bf16_t* __restrict__ out, int n4) {
  const int stride = gridDim.x * blockDim.x;
  for (int i = blockIdx.x * blockDim.x + threadIdx.x; i < n4; i += stride) {
    const float4 v = ((const float4*)in)[i];
    bf16x4 o = { (bf16_t)v.x, (bf16_t)v.y, (bf16_t)v.z, (bf16_t)v.w };
    ((bf16x4*)out)[i] = o;
  }
}

// oT[z][n][k] = w_z[k][n], fp32 -> bf16, 1024x1024 each; z concatenated -> [3072][1024]
__global__ void transpose_w3(const float* __restrict__ w0, const float* __restrict__ w1,
                             const float* __restrict__ w2, bf16_t* __restrict__ oT) {
  const float* w = blockIdx.z == 0 ? w0 : (blockIdx.z == 1 ? w1 : w2);
  bf16_t* o = oT + (size_t)blockIdx.z * D_ * D_;
  __shared__ float t[32][33];
  const int tx = threadIdx.x, ty = threadIdx.y;
  const int x  = blockIdx.x * 32 + tx;
  const int y0 = blockIdx.y * 32;
  #pragma unroll
  for (int j = 0; j < 4; ++j)
    t[ty + j * 8][tx] = w[(size_t)(y0 + ty + j * 8) * D_ + x];
  __syncthreads();
  const int x2 = y0 + tx;
  const int y2 = blockIdx.x * 32;
  #pragma unroll
  for (int j = 0; j < 4; ++j)
    o[(size_t)(y2 + ty + j * 8) * D_ + x2] = (bf16_t)t[tx][ty + j * 8];
}

// out[C][R] = in[r][coff + c] for r<R, c<C; in has leading dim ld_in (bf16)
__global__ void transpose_bf16(const bf16_t* __restrict__ in, int ld_in, int coff,
                               bf16_t* __restrict__ out, int R, int C) {
  __shared__ bf16_t t[32][34];
  const int tx = threadIdx.x, ty = threadIdx.y;
  const int x  = blockIdx.x * 32 + tx;
  const int y0 = blockIdx.y * 32;
  #pragma unroll
  for (int j = 0; j < 4; ++j)
    t[ty + j * 8][tx] = in[(size_t)(y0 + ty + j * 8) * ld_in + coff + x];
  __syncthreads();
  const int x2 = y0 + tx;
  const int y2 = blockIdx.x * 32;
  #pragma unroll
  for (int j = 0; j < 4; ++j)
    out[(size_t)(y2 + ty + j * 8) * R + x2] = t[tx][ty + j * 8];
}

extern "C" void kernel_launch(void* const* d_in, const int* in_sizes, int n_in,
                              void* d_out, int out_size, void* d_ws, size_t ws_size,
                              hipStream_t stream) {
  const float* x  = (const float*)d_in[0];
  // d_in[1] = causal mask, structurally known -> ignored
  const float* wq = (const float*)d_in[2];
  const float* bq = (const float*)d_in[3];
  const float* wk = (const float*)d_in[4];
  const float* bk = (const float*)d_in[5];
  const float* wv = (const float*)d_in[6];
  const float* bv = (const float*)d_in[7];
  float* out = (float*)d_out;

  // workspace layout (bf16 elems), ~118 MB total
  bf16_t* xb   = (bf16_t*)d_ws;                    // [8192][1024]    16 MB
  bf16_t* wT   = xb  + (size_t)M_ * D_;            // [3072][1024]     6 MB (W^T, q|k|v)
  bf16_t* qkv  = wT  + (size_t)N3_ * D_;           // [8192][3072]    48 MB (q pre-scaled)
  bf16_t* vbT  = qkv + (size_t)M_ * N3_;           // [1024][8192]    16 MB (V^T)
  bf16_t* Sb   = vbT + (size_t)M_ * D_;            // [4][2048][2048] 32 MB bf16
  bf16_t* Pfull = qkv;                             // [4][2048][2048] 32 MB (aliases dead qkv)

  const size_t SMEM = 131072;   // 128 KiB: A dbuf 64K + B dbuf 64K

  cvt_f32_bf16<<<1024, 256, 0, stream>>>(x, xb, M_ * D_ / 4);
  transpose_w3<<<dim3(32, 32, 3), dim3(32, 8), 0, stream>>>(wq, wk, wv, wT);

  // fused projection GEMM: C[8192][3072] = xb @ wT^T, bias/scale per column
  gemm32<true, false, false, true><<<dim3(N3_ / 256, M_ / 256), 512, SMEM, stream>>>(
      xb, D_, 0, wT, D_, 0, qkv, N3_, 0, bq, bk, bv, D_);

  // V^T from qkv columns [2048,3072)
  transpose_bf16<<<dim3(D_ / 32, M_ / 32), dim3(32, 8), 0, stream>>>(qkv, N3_, 2 * D_, vbT, M_, D_);

  // QK^T for all batches (Q = cols [0,1024), K = cols [1024,2048)), bf16 logits
  gemm32<true, true, false, false><<<dim3(L_ / 256, L_ / 256, B_), 512, SMEM, stream>>>(
      qkv, N3_, (long)L_ * N3_, qkv + D_, N3_, (long)L_ * N3_, Sb, L_, (long)L_ * L_,
      nullptr, nullptr, nullptr, D_);

  // softmax for all batches (writes Pfull over dead qkv)
  softmax_causal<<<dim3(L_, B_), 256, 0, stream>>>(Sb, Pfull);

  // PV for all batches
  gemm32<false, false, true, false><<<dim3(D_ / 256, L_ / 256, B_), 512, SMEM, stream>>>(
      Pfull, L_, (long)L_ * L_, vbT, M_, (long)L_, out, D_, (long)L_ * D_,
      nullptr, nullptr, nullptr, L_);
}